// Round 2
// baseline (47.698 us; speedup 1.0000x reference)
//
#include <hip/hip_runtime.h>
#include <hip/hip_bf16.h>
#include <math.h>

// Problem constants (fixed by reference): N=2000 nodes, B=2000 bills, D=32, K=3.
#define NN  2000
#define NB  2000
#define DD  32
#define BT  8       // bills per block tile (2000/8 = 250 y-blocks)
#define TPB 256

__global__ __launch_bounds__(TPB, 2) void pol2vec_kernel(
    const int*   __restrict__ events,   // [N,B] 0/1
    const float* __restrict__ tarr,     // [B]
    const float* __restrict__ beta,     // [B]
    const float* __restrict__ gamma,    // [N]
    const float* __restrict__ zb,       // [B,D]
    const float* __restrict__ zp,       // [K,N,D]
    float*       __restrict__ out)      // [1]
{
    __shared__ float s_zb[BT][DD];
    __shared__ float s_t[BT];
    __shared__ float s_be[BT];
    __shared__ float s_red[TPB / 64];

    const int tid = threadIdx.x;
    const int n   = blockIdx.x * TPB + tid;
    const int b0  = blockIdx.y * BT;

    // Stage the bill tile: z_b rows (256 floats) + t + beta. Fully coalesced.
    if (tid < BT * DD) {
        s_zb[tid / DD][tid % DD] = zb[(size_t)b0 * DD + tid];
    }
    if (tid < BT) {
        s_t[tid]  = tarr[b0 + tid];
        s_be[tid] = beta[b0 + tid];
    }
    __syncthreads();

    float acc = 0.f;
    if (n < NN) {
        // This politician's K=3 coefficient rows -> 96 VGPRs (launch_bounds
        // gives the allocator room: cap 256, expect ~140 used).
        float A[DD], Bv[DD], Cv[DD];
        const float* baseA = zp + (size_t)n * DD;
        const float* baseB = zp + (size_t)NN * DD + (size_t)n * DD;
        const float* baseC = zp + (size_t)2 * NN * DD + (size_t)n * DD;
#pragma unroll
        for (int i = 0; i < DD / 4; ++i) {
            float4 a = ((const float4*)baseA)[i];
            float4 b = ((const float4*)baseB)[i];
            float4 c = ((const float4*)baseC)[i];
            A[4 * i + 0] = a.x; A[4 * i + 1] = a.y; A[4 * i + 2] = a.z; A[4 * i + 3] = a.w;
            Bv[4 * i + 0] = b.x; Bv[4 * i + 1] = b.y; Bv[4 * i + 2] = b.z; Bv[4 * i + 3] = b.w;
            Cv[4 * i + 0] = c.x; Cv[4 * i + 1] = c.y; Cv[4 * i + 2] = c.z; Cv[4 * i + 3] = c.w;
        }
        const float g = gamma[n];

        // Preload this thread's 8 event bits (two aligned int4) -> sign floats.
        const int* evrow = events + (size_t)n * NB + b0;
        int4 e0 = ((const int4*)evrow)[0];
        int4 e1 = ((const int4*)evrow)[1];
        float sg[BT];
        sg[0] = e0.x ? 1.f : -1.f;  sg[1] = e0.y ? 1.f : -1.f;
        sg[2] = e0.z ? 1.f : -1.f;  sg[3] = e0.w ? 1.f : -1.f;
        sg[4] = e1.x ? 1.f : -1.f;  sg[5] = e1.y ? 1.f : -1.f;
        sg[6] = e1.z ? 1.f : -1.f;  sg[7] = e1.w ? 1.f : -1.f;

#pragma unroll 2
        for (int b = 0; b < BT; ++b) {
            const float t  = s_t[b];
            const float ht = 0.5f * t;
            float d2a = 0.f, d2b = 0.f, d2c = 0.f, d2d = 0.f;
            const float4* z4 = (const float4*)s_zb[b];
#pragma unroll
            for (int i = 0; i < DD / 4; ++i) {
                float4 z = z4[i];
                // pos = A + t*(B + (t/2)*C)  (Horner)
                float p0 = fmaf(t, fmaf(ht, Cv[4 * i + 0], Bv[4 * i + 0]), A[4 * i + 0]);
                float p1 = fmaf(t, fmaf(ht, Cv[4 * i + 1], Bv[4 * i + 1]), A[4 * i + 1]);
                float p2 = fmaf(t, fmaf(ht, Cv[4 * i + 2], Bv[4 * i + 2]), A[4 * i + 2]);
                float p3 = fmaf(t, fmaf(ht, Cv[4 * i + 3], Bv[4 * i + 3]), A[4 * i + 3]);
                float f0 = p0 - z.x, f1 = p1 - z.y, f2 = p2 - z.z, f3 = p3 - z.w;
                d2a = fmaf(f0, f0, d2a);
                d2b = fmaf(f1, f1, d2b);
                d2c = fmaf(f2, f2, d2c);
                d2d = fmaf(f3, f3, d2d);
            }
            float d2 = (d2a + d2b) + (d2c + d2d);
            float L = g + s_be[b] - sqrtf(d2);
            float s = sg[b] * L;
            // -log_sigmoid(s) = max(-s,0) + log(1+exp(-|s|)); hw exp/log,
            // abs err <= ~6e-8/term, irrelevant vs 1e5 threshold.
            acc += fmaxf(-s, 0.f) + __logf(1.f + __expf(-fabsf(s)));
        }
    }

    // Wave64 shuffle reduction, then cross-wave via LDS, one atomic per block.
#pragma unroll
    for (int o = 32; o > 0; o >>= 1) acc += __shfl_down(acc, o, 64);
    const int wave = tid >> 6;
    const int lane = tid & 63;
    if (lane == 0) s_red[wave] = acc;
    __syncthreads();
    if (tid == 0) {
        float s = 0.f;
#pragma unroll
        for (int w = 0; w < TPB / 64; ++w) s += s_red[w];
        atomicAdd(out, s);
    }
}

extern "C" void kernel_launch(void* const* d_in, const int* in_sizes, int n_in,
                              void* d_out, int out_size, void* d_ws, size_t ws_size,
                              hipStream_t stream) {
    const int*   events = (const int*)d_in[0];    // [N,B]
    const float* tarr   = (const float*)d_in[1];  // [B]
    const float* beta   = (const float*)d_in[2];  // [B]
    const float* gamma  = (const float*)d_in[3];  // [N]
    const float* zb     = (const float*)d_in[4];  // [B,D]
    const float* zp     = (const float*)d_in[5];  // [K,N,D]
    float* out = (float*)d_out;

    // d_out is poisoned once (0xAA) and never re-poisoned between replays:
    // zero it ourselves every launch (graph-capture-safe async memset).
    hipMemsetAsync(out, 0, (size_t)out_size * sizeof(float), stream);

    dim3 grid((NN + TPB - 1) / TPB, NB / BT);
    pol2vec_kernel<<<grid, TPB, 0, stream>>>(events, tarr, beta, gamma, zb, zp, out);
}

// Round 3
// 37.079 us; speedup vs baseline: 1.2864x; 1.2864x over previous
//
#include <hip/hip_runtime.h>
#include <hip/hip_bf16.h>
#include <math.h>

// Problem constants (fixed by reference): N=2000 nodes, B=2000 bills, D=32, K=3.
#define NN  2000
#define NB  2000
#define DD  32
#define NP  16      // politicians per block (inner uniform loop)
#define TPB 256     // bills per block, one per thread

// Lanes = bills (coalesced events/t/beta), politicians = uniform loop
// (zp/gamma become scalar loads). zb row lives in 32 VGPRs per thread.
__global__ __launch_bounds__(TPB) void pol2vec_kernel(
    const int*   __restrict__ events,   // [N,B] 0/1
    const float* __restrict__ tarr,     // [B]
    const float* __restrict__ beta,     // [B]
    const float* __restrict__ gamma,    // [N]
    const float* __restrict__ zb,       // [B,D]
    const float* __restrict__ zp,       // [K,N,D]
    float*       __restrict__ out)      // [1]
{
    __shared__ float s_red[TPB / 64];

    const int tid = threadIdx.x;
    const int b   = blockIdx.x * TPB + tid;   // this thread's bill
    const int n0  = blockIdx.y * NP;          // block's politician range
    const bool valid = (b < NB);
    const int bc  = valid ? b : 0;            // clamped (contribution masked)

    // Per-lane bill state in registers (loaded once, coalesced).
    const float t   = tarr[bc];
    const float bb  = beta[bc];
    const float t2h = 0.5f * t * t;           // t^2 / 2!

    float4 zr[DD / 4];
    const float4* zb4 = (const float4*)(zb + (size_t)bc * DD);
#pragma unroll
    for (int i = 0; i < DD / 4; ++i) zr[i] = zb4[i];

    float acc = 0.f;

    for (int j = 0; j < NP; ++j) {
        const int n = n0 + j;
        const float g = gamma[n];                              // uniform -> SGPR
        // Coalesced per-lane event bit for (n, b).
        const float sgn = (events[(size_t)n * NB + bc] != 0) ? 1.f : -1.f;
        // Wave-uniform coefficient rows -> scalar loads.
        const float4* pA = (const float4*)(zp + (size_t)n * DD);
        const float4* pB = (const float4*)(zp + ((size_t)NN + n) * DD);
        const float4* pC = (const float4*)(zp + ((size_t)2 * NN + n) * DD);

        float d2a = 0.f, d2b = 0.f, d2c = 0.f, d2d = 0.f;
#pragma unroll
        for (int i = 0; i < DD / 4; ++i) {
            const float4 a  = pA[i];
            const float4 bv = pB[i];
            const float4 cv = pC[i];
            const float4 z  = zr[i];
            // pos = A + t*B + (t^2/2)*C
            float p0 = fmaf(t2h, cv.x, fmaf(t, bv.x, a.x));
            float p1 = fmaf(t2h, cv.y, fmaf(t, bv.y, a.y));
            float p2 = fmaf(t2h, cv.z, fmaf(t, bv.z, a.z));
            float p3 = fmaf(t2h, cv.w, fmaf(t, bv.w, a.w));
            float f0 = p0 - z.x, f1 = p1 - z.y, f2 = p2 - z.z, f3 = p3 - z.w;
            d2a = fmaf(f0, f0, d2a);
            d2b = fmaf(f1, f1, d2b);
            d2c = fmaf(f2, f2, d2c);
            d2d = fmaf(f3, f3, d2d);
        }
        const float d2 = (d2a + d2b) + (d2c + d2d);
        const float L  = g + bb - sqrtf(d2);
        const float s  = sgn * L;
        // -log_sigmoid(s) = max(-s,0) + log(1+exp(-|s|)); hw exp/log.
        acc += fmaxf(-s, 0.f) + __logf(1.f + __expf(-fabsf(s)));
    }

    if (!valid) acc = 0.f;

    // Wave64 shuffle reduction, then cross-wave via LDS, one atomic per block.
#pragma unroll
    for (int o = 32; o > 0; o >>= 1) acc += __shfl_down(acc, o, 64);
    const int wave = tid >> 6;
    const int lane = tid & 63;
    if (lane == 0) s_red[wave] = acc;
    __syncthreads();
    if (tid == 0) {
        float s = 0.f;
#pragma unroll
        for (int w = 0; w < TPB / 64; ++w) s += s_red[w];
        atomicAdd(out, s);
    }
}

extern "C" void kernel_launch(void* const* d_in, const int* in_sizes, int n_in,
                              void* d_out, int out_size, void* d_ws, size_t ws_size,
                              hipStream_t stream) {
    const int*   events = (const int*)d_in[0];    // [N,B]
    const float* tarr   = (const float*)d_in[1];  // [B]
    const float* beta   = (const float*)d_in[2];  // [B]
    const float* gamma  = (const float*)d_in[3];  // [N]
    const float* zb     = (const float*)d_in[4];  // [B,D]
    const float* zp     = (const float*)d_in[5];  // [K,N,D]
    float* out = (float*)d_out;

    // d_out is poisoned once (0xAA) and never re-poisoned between replays:
    // zero it ourselves every launch (graph-capture-safe async memset).
    hipMemsetAsync(out, 0, (size_t)out_size * sizeof(float), stream);

    dim3 grid((NB + TPB - 1) / TPB, NN / NP);
    pol2vec_kernel<<<grid, TPB, 0, stream>>>(events, tarr, beta, gamma, zb, zp, out);
}